// Round 1
// baseline (55.835 us; speedup 1.0000x reference)
//
#include <hip/hip_runtime.h>
#include <hip/hip_bf16.h>
#include <hip/hip_fp16.h>

typedef _Float16 f16x8 __attribute__((ext_vector_type(8)));
typedef float f32x4 __attribute__((ext_vector_type(4)));

#define N_PTS 32768
#define NCHUNK 65   // 64 h-chunks + 1 bias chunk (h == 1)

// ---- prep: convert W2 (fp32 [64][4096]) and b2 (fp32 [4096]) into f16
// fragment-major layout in ws:
//   element t = (((c*2+s)*4+nt)*64 + lane)*8 + j
//   holds Wf[kk][o] with kk = c*64 + s*32 + (lane>>4)*8 + j,  o = nt*16 + (lane&15)
//   Wf[kk][o] = W2flat[kk*64 + o] ; chunk c==64 is b2 (bias as extra K rows).
__global__ void prep_kernel(const float* __restrict__ W2,
                            const float* __restrict__ b2,
                            _Float16* __restrict__ wsB) {
    int t = blockIdx.x * blockDim.x + threadIdx.x;
    if (t >= NCHUNK * 4096) return;
    int j    = t & 7;
    int lane = (t >> 3) & 63;
    int nt   = (t >> 9) & 3;
    int s    = (t >> 11) & 1;
    int c    = t >> 12;
    int kl = s * 32 + ((lane >> 4) << 3) + j;   // 0..63 within chunk
    int o  = nt * 16 + (lane & 15);
    float v;
    if (c < 64) v = W2[(c * 64 + kl) * 64 + o];
    else        v = b2[kl * 64 + o];
    wsB[t] = (_Float16)v;
}

// ---- main fused kernel ----
// grid = 256 blocks, 128 threads (2 waves). Each wave: 64 rows x 64 cols.
__global__ __launch_bounds__(128) void main_kernel(
    const float* __restrict__ x, const float* __restrict__ gridp,
    const float* __restrict__ W1, const float* __restrict__ b1,
    const _Float16* __restrict__ wsB, float* __restrict__ out) {

  __shared__ float h_lds[128][65];   // stride 65 (==1 mod 32): conflict-free

  const int tid  = threadIdx.x;
  const int lane = tid & 63;
  const int wave = tid >> 6;
  const int rowblk = blockIdx.x * 128;

  // phase 1: h[row][k] = gelu(grid @ W1 + b1), exact gelu. One row per thread.
  {
    int r = rowblk + tid;
    float g0 = gridp[r * 3 + 0], g1 = gridp[r * 3 + 1], g2 = gridp[r * 3 + 2];
    #pragma unroll 4
    for (int k = 0; k < 64; ++k) {
      float v = g0 * W1[k] + g1 * W1[64 + k] + g2 * W1[128 + k] + b1[k];
      float h = 0.5f * v * (1.0f + erff(v * 0.7071067811865476f));
      h_lds[tid][k] = h;
    }
    h_lds[tid][64] = 1.0f;   // bias chunk: h == 1
  }
  __syncthreads();

  const int rbase = wave * 64;        // row base within block for this wave
  const int mrow  = lane & 15;        // A row within 16-tile / D col
  const int kgrp  = lane >> 4;        // 0..3

  // x fragments: xf[m][s][j] = x[row, s*32 + kgrp*8 + j]  (fixed across K loop)
  f16x8 xf[4][2];
  #pragma unroll
  for (int m = 0; m < 4; ++m) {
    #pragma unroll
    for (int s = 0; s < 2; ++s) {
      const float* xp = x + (rowblk + rbase + m * 16 + mrow) * 64 + s * 32 + kgrp * 8;
      f16x8 v;
      #pragma unroll
      for (int j = 0; j < 8; ++j) v[j] = (_Float16)xp[j];
      xf[m][s] = v;
    }
  }

  f32x4 acc[4][4];
  #pragma unroll
  for (int m = 0; m < 4; ++m)
    #pragma unroll
    for (int n = 0; n < 4; ++n)
      acc[m][n] = (f32x4){0.f, 0.f, 0.f, 0.f};

  const _Float16* bp = wsB + lane * 8;   // + (c*8 + s*4 + nt)*512 elements

  // fragment loads (8 per chunk: q = s*4 + nt), double-buffered in registers
  auto LOADB = [&](f16x8* b, int c) {
    #pragma unroll
    for (int q = 0; q < 8; ++q)
      b[q] = *(const f16x8*)(bp + (c * 8 + q) * 512);
  };
  auto COMPUTE = [&](const f16x8* b, int c) {
    #pragma unroll
    for (int m = 0; m < 4; ++m) {
      float hv = h_lds[rbase + m * 16 + mrow][c];
      _Float16 hh = (_Float16)hv;
      f16x8 hs = {hh, hh, hh, hh, hh, hh, hh, hh};
      f16x8 a0 = xf[m][0] * hs;   // v_pk_mul_f16: A-frag = h_k * x-frag
      f16x8 a1 = xf[m][1] * hs;
      #pragma unroll
      for (int n = 0; n < 4; ++n) {
        acc[m][n] = __builtin_amdgcn_mfma_f32_16x16x32_f16(a0, b[n],     acc[m][n], 0, 0, 0);
        acc[m][n] = __builtin_amdgcn_mfma_f32_16x16x32_f16(a1, b[4 + n], acc[m][n], 0, 0, 0);
      }
    }
  };

  f16x8 bufA[8], bufB[8];
  LOADB(bufA, 0);
  for (int c = 0; c < 64; c += 2) {
    LOADB(bufB, c + 1);
    COMPUTE(bufA, c);
    LOADB(bufA, c + 2);      // c+2 <= 64 == bias chunk
    COMPUTE(bufB, c + 1);
  }
  COMPUTE(bufA, 64);

  // epilogue: D col = lane&15, row = kgrp*4 + r  (verified C/D layout)
  #pragma unroll
  for (int m = 0; m < 4; ++m) {
    #pragma unroll
    for (int n = 0; n < 4; ++n) {
      int row = rowblk + rbase + m * 16 + kgrp * 4;
      #pragma unroll
      for (int r = 0; r < 4; ++r)
        out[(row + r) * 64 + n * 16 + mrow] = acc[m][n][r];
    }
  }
}

extern "C" void kernel_launch(void* const* d_in, const int* in_sizes, int n_in,
                              void* d_out, int out_size, void* d_ws, size_t ws_size,
                              hipStream_t stream) {
  const float* x    = (const float*)d_in[0];
  const float* grid = (const float*)d_in[1];
  const float* W1   = (const float*)d_in[2];
  const float* b1   = (const float*)d_in[3];
  const float* W2   = (const float*)d_in[4];
  const float* b2   = (const float*)d_in[5];
  float* out = (float*)d_out;
  _Float16* wsB = (_Float16*)d_ws;   // needs 65*4096*2 = 532480 bytes

  hipLaunchKernelGGL(prep_kernel, dim3((NCHUNK * 4096 + 255) / 256), dim3(256), 0, stream,
                     W2, b2, wsB);
  hipLaunchKernelGGL(main_kernel, dim3(N_PTS / 128), dim3(128), 0, stream,
                     x, grid, W1, b1, wsB, out);
}

// Round 2
// 32.740 us; speedup vs baseline: 1.7054x; 1.7054x over previous
//
#include <hip/hip_runtime.h>
#include <hip/hip_bf16.h>
#include <hip/hip_fp16.h>

typedef _Float16 f16x8 __attribute__((ext_vector_type(8)));
typedef float f32x4 __attribute__((ext_vector_type(4)));

#define N_PTS 32768
#define NCHUNK 65       // 64 h-chunks + 1 bias chunk (h == 1)
#define ROWS 64         // rows per block
#define H_STRIDE 66     // f16 elements; 66*2B=132B -> 33 banks/row, conflict-free
#define P_STRIDE 68     // f32 elements; 68*4B=272B, 16B-aligned rows
#define P_WAVE (ROWS * P_STRIDE)   // 4352 floats per wave partial

// ---- prep: convert W2 (fp32 [64][4096]) and b2 (fp32 [4096]) into f16
// fragment-major layout in ws:
//   element t = (((c*2+s)*4+nt)*64 + lane)*8 + j
//   holds Wf[kk][o] with kk = c*64 + s*32 + (lane>>4)*8 + j,  o = nt*16 + (lane&15)
//   Wf[kk][o] = W2flat[kk*64 + o] ; chunk c==64 is b2 (bias as extra K rows).
__global__ void prep_kernel(const float* __restrict__ W2,
                            const float* __restrict__ b2,
                            _Float16* __restrict__ wsB) {
    int t = blockIdx.x * blockDim.x + threadIdx.x;
    if (t >= NCHUNK * 4096) return;
    int j    = t & 7;
    int lane = (t >> 3) & 63;
    int nt   = (t >> 9) & 3;
    int s    = (t >> 11) & 1;
    int c    = t >> 12;
    int kl = s * 32 + ((lane >> 4) << 3) + j;   // 0..63 within chunk
    int o  = nt * 16 + (lane & 15);
    float v;
    if (c < 64) v = W2[(c * 64 + kl) * 64 + o];
    else        v = b2[kl * 64 + o];
    wsB[t] = (_Float16)v;
}

// ---- main fused kernel ----
// 512 blocks x 256 threads (4 waves). Block owns 64 rows; waves K-split the
// 65 chunks (wave w: c = w, w+4, ...), partials reduced via LDS.
__global__ __launch_bounds__(256, 2) void main_kernel(
    const float* __restrict__ x, const float* __restrict__ gridp,
    const float* __restrict__ W1, const float* __restrict__ b1,
    const _Float16* __restrict__ wsB, float* __restrict__ out) {

  __shared__ _Float16 h_lds[ROWS][H_STRIDE];
  __shared__ float part[4 * P_WAVE];

  const int tid  = threadIdx.x;
  const int lane = tid & 63;
  const int wave = tid >> 6;
  const int rowblk = blockIdx.x * ROWS;

  // phase 1: h[row][k] = gelu(grid @ W1 + b1). 4 threads per row, 16 k each.
  {
    int row = tid >> 2;
    int kb  = (tid & 3) * 16;
    int r = rowblk + row;
    float g0 = gridp[r * 3 + 0], g1 = gridp[r * 3 + 1], g2 = gridp[r * 3 + 2];
    #pragma unroll 4
    for (int k = kb; k < kb + 16; ++k) {
      float v = g0 * W1[k] + g1 * W1[64 + k] + g2 * W1[128 + k] + b1[k];
      float h = 0.5f * v * (1.0f + erff(v * 0.7071067811865476f));
      h_lds[row][k] = (_Float16)h;
    }
    if ((tid & 3) == 3) h_lds[row][64] = (_Float16)1.0f;  // bias chunk: h == 1
  }
  __syncthreads();

  const int mrow = lane & 15;        // A row within 16-tile / D col
  const int kgrp = lane >> 4;        // 0..3

  // x fragments: xf[m][s][j] = x[row, s*32 + kgrp*8 + j]  (fixed across K loop)
  f16x8 xf[4][2];
  #pragma unroll
  for (int m = 0; m < 4; ++m) {
    #pragma unroll
    for (int s = 0; s < 2; ++s) {
      const float* xp = x + (rowblk + m * 16 + mrow) * 64 + s * 32 + kgrp * 8;
      f16x8 v;
      #pragma unroll
      for (int j = 0; j < 8; ++j) v[j] = (_Float16)xp[j];
      xf[m][s] = v;
    }
  }

  f32x4 acc[4][4];
  #pragma unroll
  for (int m = 0; m < 4; ++m)
    #pragma unroll
    for (int n = 0; n < 4; ++n)
      acc[m][n] = (f32x4){0.f, 0.f, 0.f, 0.f};

  const _Float16* bp = wsB + lane * 8;   // + (c*8 + q)*512 elements

  auto LOADB = [&](f16x8* b, int c) {
    #pragma unroll
    for (int q = 0; q < 8; ++q)
      b[q] = *(const f16x8*)(bp + (c * 8 + q) * 512);
  };
  auto COMPUTE = [&](const f16x8* b, int c) {
    #pragma unroll
    for (int m = 0; m < 4; ++m) {
      _Float16 hh = h_lds[m * 16 + mrow][c];
      f16x8 hs = {hh, hh, hh, hh, hh, hh, hh, hh};
      f16x8 a0 = xf[m][0] * hs;   // v_pk_mul_f16: A-frag = h_k * x-frag
      f16x8 a1 = xf[m][1] * hs;
      #pragma unroll
      for (int n = 0; n < 4; ++n) {
        acc[m][n] = __builtin_amdgcn_mfma_f32_16x16x32_f16(a0, b[n],     acc[m][n], 0, 0, 0);
        acc[m][n] = __builtin_amdgcn_mfma_f32_16x16x32_f16(a1, b[4 + n], acc[m][n], 0, 0, 0);
      }
    }
  };

  // K-split: wave w handles chunks c = w, w+4, ... (< 65). wave0 gets 17.
  const int nch = (wave == 0) ? 17 : 16;
  f16x8 bufA[8], bufB[8];
  LOADB(bufA, wave);
  int i = 1;
  for (; i + 1 < nch; i += 2) {
    LOADB(bufB, wave + 4 * i);
    COMPUTE(bufA, wave + 4 * (i - 1));
    LOADB(bufA, wave + 4 * (i + 1));
    COMPUTE(bufB, wave + 4 * i);
  }
  if (i < nch) {                       // odd tail (nch even: 16)
    LOADB(bufB, wave + 4 * i);
    COMPUTE(bufA, wave + 4 * (i - 1));
    COMPUTE(bufB, wave + 4 * i);
  } else {                             // nch odd: 17 (wave 0)
    COMPUTE(bufA, wave + 4 * (nch - 1));
  }

  // write per-wave partials to LDS (row = m*16+kgrp*4+r, col = n*16+mrow)
  {
    float* pw = part + wave * P_WAVE;
    #pragma unroll
    for (int m = 0; m < 4; ++m)
      #pragma unroll
      for (int n = 0; n < 4; ++n)
        #pragma unroll
        for (int r = 0; r < 4; ++r)
          pw[(m * 16 + kgrp * 4 + r) * P_STRIDE + n * 16 + mrow] = acc[m][n][r];
  }
  __syncthreads();

  // reduce 4 partials and store. 4 threads/row, 16 cols each (4x f32x4).
  {
    int row = tid >> 2;
    int cb  = (tid & 3) * 16;
    const float* p0 = part + row * P_STRIDE + cb;
    float* op = out + (rowblk + row) * 64 + cb;
    #pragma unroll
    for (int j = 0; j < 4; ++j) {
      f32x4 s = *(const f32x4*)(p0 + j * 4);
      #pragma unroll
      for (int w = 1; w < 4; ++w)
        s += *(const f32x4*)(p0 + w * P_WAVE + j * 4);
      *(f32x4*)(op + j * 4) = s;
    }
  }
}

extern "C" void kernel_launch(void* const* d_in, const int* in_sizes, int n_in,
                              void* d_out, int out_size, void* d_ws, size_t ws_size,
                              hipStream_t stream) {
  const float* x    = (const float*)d_in[0];
  const float* grid = (const float*)d_in[1];
  const float* W1   = (const float*)d_in[2];
  const float* b1   = (const float*)d_in[3];
  const float* W2   = (const float*)d_in[4];
  const float* b2   = (const float*)d_in[5];
  float* out = (float*)d_out;
  _Float16* wsB = (_Float16*)d_ws;   // needs 65*4096*2 = 532480 bytes

  hipLaunchKernelGGL(prep_kernel, dim3((NCHUNK * 4096 + 255) / 256), dim3(256), 0, stream,
                     W2, b2, wsB);
  hipLaunchKernelGGL(main_kernel, dim3(N_PTS / ROWS), dim3(256), 0, stream,
                     x, grid, W1, b1, wsB, out);
}